// Round 6
// baseline (246.034 us; speedup 1.0000x reference)
//
#include <hip/hip_runtime.h>

#define L_SEQ 2688
#define DIM   1536
#define NH    12
#define HD    128
#define BLK_TOK 1344   // 3*H*W
#define HW_   448      // H*W
#define W_    28

typedef unsigned short u16;
typedef unsigned int   u32;
typedef __attribute__((ext_vector_type(4))) float f32x4;
typedef __attribute__((ext_vector_type(8))) short s16x8;

__device__ __forceinline__ u16 f2b(float f) {
    u32 u = __builtin_bit_cast(u32, f);
    return (u16)((u + 0x7FFFu + ((u >> 16) & 1u)) >> 16);   // RNE
}
__device__ __forceinline__ float b2f(u16 b) {
    return __builtin_bit_cast(float, (u32)b << 16);
}
__device__ __forceinline__ u32 cvt_pk_bf16(float lo, float hi) {
    u32 r;
    asm("v_cvt_pk_bf16_f32 %0, %1, %2" : "=v"(r) : "v"(lo), "v"(hi));
    return r;
}

// ---------------------------------------------------------------- x -> bf16
__global__ __launch_bounds__(256) void k_cvt_x(const float* __restrict__ x,
                                               u16* __restrict__ xb, int n4) {
    int i = blockIdx.x * 256 + threadIdx.x;
    int stride = gridDim.x * 256;
    for (; i < n4; i += stride) {
        float4 v = ((const float4*)x)[i];
        ushort4 o;
        o.x = f2b(v.x); o.y = f2b(v.y); o.z = f2b(v.z); o.w = f2b(v.w);
        ((ushort4*)xb)[i] = o;
    }
}

// ------------------------------------- W (f32 [K][N]) -> Wt (bf16 [N][K])
__global__ __launch_bounds__(256) void k_trans_w(const float* __restrict__ w0,
                                                 const float* __restrict__ w1,
                                                 const float* __restrict__ w2,
                                                 const float* __restrict__ w3,
                                                 u16* __restrict__ wt_all) {
    const float* w = blockIdx.z == 0 ? w0 : blockIdx.z == 1 ? w1 : blockIdx.z == 2 ? w2 : w3;
    u16* wt = wt_all + (size_t)blockIdx.z * DIM * DIM;
    __shared__ float t[64][65];
    const int k0 = blockIdx.y * 64, n0 = blockIdx.x * 64;
    const int c = threadIdx.x & 63, rg = threadIdx.x >> 6;
#pragma unroll
    for (int it = 0; it < 16; ++it) {
        int r = rg * 16 + it;
        t[r][c] = w[(size_t)(k0 + r) * DIM + n0 + c];
    }
    __syncthreads();
#pragma unroll
    for (int it = 0; it < 16; ++it) {
        int r = rg * 16 + it;
        wt[(size_t)(n0 + r) * DIM + k0 + c] = f2b(t[c][r]);
    }
}

// ------------------------------------------------- GEMM: C = A*Bt^T + bias
template<int OUTF>
__global__ __launch_bounds__(256, 2) void k_gemm(const u16* __restrict__ A,
                                                 const u16* __restrict__ Bt_all,
                                                 const float* __restrict__ b0,
                                                 const float* __restrict__ b1,
                                                 const float* __restrict__ b2,
                                                 void* __restrict__ out_all) {
    const int z = blockIdx.z;
    const u16* Bt = Bt_all + (size_t)z * DIM * DIM;
    const float* bias = z == 0 ? b0 : z == 1 ? b1 : b2;

    __shared__ u16 lA[128 * 32];
    __shared__ u16 lB[128 * 32];
    const int tid = threadIdx.x, lane = tid & 63, wid = tid >> 6;
    const int wm = wid >> 1, wn = wid & 1;
    const int bm = blockIdx.y, bn = blockIdx.x;
    const int lr = lane & 15, lg = lane >> 4;

    f32x4 acc[4][4] = {};

    for (int kt = 0; kt < DIM / 32; ++kt) {
#pragma unroll
        for (int i = 0; i < 2; ++i) {
            int s = wid * 128 + i * 64 + lane;        // 16B slot id
            int row = s >> 2, c16 = s & 3;            // 4 slots per 32-elem row
            const u16* ga = A + (size_t)(bm * 128 + row) * DIM + kt * 32 + c16 * 8;
            __builtin_amdgcn_global_load_lds(
                (const __attribute__((address_space(1))) u32*)ga,
                (__attribute__((address_space(3))) u32*)&lA[(wid * 128 + i * 64) * 8],
                16, 0, 0);
            const u16* gb = Bt + (size_t)(bn * 128 + row) * DIM + kt * 32 + c16 * 8;
            __builtin_amdgcn_global_load_lds(
                (const __attribute__((address_space(1))) u32*)gb,
                (__attribute__((address_space(3))) u32*)&lB[(wid * 128 + i * 64) * 8],
                16, 0, 0);
        }
        __syncthreads();
        s16x8 af[4], bf[4];
#pragma unroll
        for (int m = 0; m < 4; ++m)
            af[m] = *(const s16x8*)&lA[(wm * 64 + m * 16 + lr) * 32 + lg * 8];
#pragma unroll
        for (int n = 0; n < 4; ++n)
            bf[n] = *(const s16x8*)&lB[(wn * 64 + n * 16 + lr) * 32 + lg * 8];
#pragma unroll
        for (int m = 0; m < 4; ++m)
#pragma unroll
            for (int n = 0; n < 4; ++n)
                acc[m][n] = __builtin_amdgcn_mfma_f32_16x16x32_bf16(af[m], bf[n], acc[m][n], 0, 0, 0);
        __syncthreads();
    }
#pragma unroll
    for (int n = 0; n < 4; ++n) {
        int col = bn * 128 + wn * 64 + n * 16 + lr;
        float bv = bias[col];
#pragma unroll
        for (int m = 0; m < 4; ++m) {
            int row0 = bm * 128 + wm * 64 + m * 16 + lg * 4;
#pragma unroll
            for (int r = 0; r < 4; ++r) {
                float v = acc[m][n][r] + bv;
                if (OUTF)
                    ((float*)out_all)[(size_t)(row0 + r) * DIM + col] = v;
                else
                    ((u16*)out_all)[(size_t)z * L_SEQ * DIM + (size_t)(row0 + r) * DIM + col] = f2b(v);
            }
        }
    }
}

// ---------------- RMSNorm(row of 1536) + RoPE -> [h][i][d]; y selects q/k
__global__ __launch_bounds__(256) void k_norm_rope(const u16* __restrict__ pre_all,
                                                   const float* __restrict__ gq,
                                                   const float* __restrict__ gk,
                                                   const float* __restrict__ freqs,
                                                   u16* __restrict__ qh,
                                                   u16* __restrict__ kh) {
    const int which = blockIdx.y;
    const u16* pre = pre_all + (size_t)which * L_SEQ * DIM;
    const float* g = which ? gk : gq;
    u16* outh = which ? kh : qh;

    const int i = blockIdx.x;
    const int t = threadIdx.x;
    const u32* prow = (const u32*)(pre + (size_t)i * DIM);  // 768 bf16 pairs

    float re[3], im[3];
    float ss = 0.f;
#pragma unroll
    for (int a = 0; a < 3; ++a) {
        u32 p = prow[t + a * 256];
        float x = b2f((u16)(p & 0xFFFFu)), y = b2f((u16)(p >> 16));
        re[a] = x; im[a] = y;
        ss += x * x + y * y;
    }
#pragma unroll
    for (int o = 32; o > 0; o >>= 1) ss += __shfl_down(ss, o, 64);
    __shared__ float sred[4];
    if ((t & 63) == 0) sred[t >> 6] = ss;
    __syncthreads();
    float rms = rsqrtf((sred[0] + sred[1] + sred[2] + sred[3]) * (1.0f / DIM) + 1e-6f);

    const int f = i / HW_;
    const int rem = i - f * HW_;
    const int hp = rem / W_;
    const int wp = rem - hp * W_;
#pragma unroll
    for (int a = 0; a < 3; ++a) {
        int j = t + a * 256;         // pair index in row: head h = j>>6, pj = j&63
        int h = j >> 6, pj = j & 63;
        float2 gg = ((const float2*)g)[j];
        float x = re[a] * rms * gg.x;
        float y = im[a] * rms * gg.y;
        int ridx = pj < 22 ? f : (pj < 43 ? hp : wp);
        float2 cs = ((const float2*)freqs)[ridx * 64 + pj];
        float ore = x * cs.x - y * cs.y;
        float oim = x * cs.y + y * cs.x;
        u32 o = (u32)f2b(ore) | ((u32)f2b(oim) << 16);
        ((u32*)outh)[(size_t)h * (L_SEQ * 64) + (size_t)i * 64 + pj] = o;
    }
}

// ------------------------------------------ v [i][h*128+d] -> vt [h][d][i]
__global__ __launch_bounds__(256) void k_vtrans(const u16* __restrict__ vpre,
                                                u16* __restrict__ vt) {
    const int i0 = blockIdx.x * 64, d0 = blockIdx.y * 64, h = blockIdx.z;
    __shared__ u16 t[64][68];
    const int c = threadIdx.x & 63, rg = threadIdx.x >> 6;
#pragma unroll
    for (int it = 0; it < 16; ++it) {
        int r = rg * 16 + it;
        t[r][c] = vpre[(size_t)(i0 + r) * DIM + h * HD + d0 + c];
    }
    __syncthreads();
#pragma unroll
    for (int it = 0; it < 16; ++it) {
        int r = rg * 16 + it;  // d index
        vt[(size_t)h * (HD * L_SEQ) + (size_t)(d0 + r) * L_SEQ + i0 + c] = t[c][r];
    }
}

// ----------------------------------------------------- flash attention v6
// v3 structure (best measured: 4 waves x 16 q-rows, K LDS-staged w/ gload_lds
// dbuf, single barrier/tile) + V read DIRECT from L2 (v5's proven path).
// LDS 72->40 KB so all 756 blocks are co-resident (~12 waves/CU).
__global__ __launch_bounds__(256, 3) void k_attn(const u16* __restrict__ qh,
                                                 const u16* __restrict__ kh,
                                                 const u16* __restrict__ vt,
                                                 u16* __restrict__ ob,
                                                 float* __restrict__ Opart,
                                                 float* __restrict__ mlp) {
    __shared__ u16 lK[2][64 * 128];   // [j][d], slot-XOR swizzled, dbuf
    __shared__ u16 lP[64 * 64];       // [qrow][j], wave-private rows

    // bijective XCD swizzle: 756 blocks, consecutive ids round-robin XCDs
    const int flat = blockIdx.x;
    const int xcd = flat & 7, idx = flat >> 3;
    const int work = (xcd < 4) ? (xcd * 95 + idx) : (380 + (xcd - 4) * 94 + idx);
    const int head = work / 63;
    const int bx = work - head * 63;
    int qt, kv0, mode;
    if (bx < 21)      { qt = bx;      kv0 = 0;  mode = 0; }
    else if (bx < 42) { qt = bx;      kv0 = 0;  mode = 1; }
    else              { qt = bx - 21; kv0 = 21; mode = 2; }

    const int tid = threadIdx.x, lane = tid & 63, wid = tid >> 6;
    const int lr = lane & 15, lg = lane >> 4;
    const size_t hOff = (size_t)head * ((size_t)L_SEQ * HD);
    const u16* Kh = kh + hOff;
    const u16* Vh = vt + hOff;
    const int qrow0 = qt * 64 + wid * 16;

    // Q fragments (B-operand): Q[qrow0+lr][32kk + 8lg ..]
    s16x8 aq[4];
#pragma unroll
    for (int kk = 0; kk < 4; ++kk)
        aq[kk] = *(const s16x8*)&qh[hOff + (size_t)(qrow0 + lr) * HD + kk * 32 + lg * 8];

    // K staging: pre-swizzled global sources, linear LDS dest (gload_lds)
    const u16* kap[4];
    int ldsb[4];
#pragma unroll
    for (int i = 0; i < 4; ++i) {
        int jrow = wid * 16 + i * 4 + lg;
        kap[i] = Kh + (size_t)(kv0 * 64 + jrow) * HD + 8 * ((lane & 15) ^ (i * 4 + lg));
        ldsb[i] = wid * 4096 + i * 1024;   // bytes
    }
#define STAGE(T, BUF)                                                              \
    {                                                                              \
        _Pragma("unroll")                                                          \
        for (int i = 0; i < 4; ++i)                                                \
            __builtin_amdgcn_global_load_lds(                                      \
                (const __attribute__((address_space(1))) u32*)(kap[i] + (size_t)(T) * 8192), \
                (__attribute__((address_space(3))) u32*)((char*)&lK[BUF][0] + ldsb[i]), 16, 0, 0); \
    }

    // V direct-from-L2 per-lane base (vt layout [h][d][i])
    const u16* Vp = Vh + (size_t)lr * L_SEQ + kv0 * 64 + lg * 8;

    f32x4 acc[8] = {};
    float mrun = -1e30f, lrun = 0.f;
    const float sc2 = 0.12751739646917983f;  // 1/sqrt(128) * log2(e)
    const int prow = wid * 16 + lr;
    const int pswz = (lr & 7) << 4;

    STAGE(0, 0);
    for (int t = 0; t < 21; ++t) {
        __syncthreads();                 // drains gload_lds for tile t
        if (t < 20) STAGE(t + 1, (t + 1) & 1);
        const u16* bK = lK[t & 1];
        const u16* Vt = Vp + t * 64;

        // S^T = K Q^T  (lane holds S[q=lr][j=16n+4lg+r])
        f32x4 sv[4] = {};
        __builtin_amdgcn_s_setprio(1);
#pragma unroll
        for (int n = 0; n < 4; ++n) {
#pragma unroll
            for (int kk = 0; kk < 4; ++kk) {
                int off = (16 * n + lr) * 256 + ((64 * kk + 16 * lg) ^ (lr << 4));
                s16x8 kf = *(const s16x8*)((const char*)bK + off);
                sv[n] = __builtin_amdgcn_mfma_f32_16x16x32_bf16(kf, aq[kk], sv[n], 0, 0, 0);
            }
        }
        __builtin_amdgcn_s_setprio(0);

        // V^T fragment loads issued NOW; latency hides under softmax
        s16x8 vf[16];
#pragma unroll
        for (int nd = 0; nd < 8; ++nd)
#pragma unroll
            for (int kk2 = 0; kk2 < 2; ++kk2)
                vf[nd * 2 + kk2] = *(const s16x8*)(Vt + (size_t)(16 * nd) * L_SEQ + kk2 * 32);

        // online softmax, row-local (2 shuffles per reduce)
        float mx = sv[0][0];
#pragma unroll
        for (int n = 0; n < 4; ++n) {
            mx = fmaxf(mx, fmaxf(fmaxf(sv[n][0], sv[n][1]), fmaxf(sv[n][2], sv[n][3])));
        }
        mx = fmaxf(mx, __shfl_xor(mx, 16, 64));
        mx = fmaxf(mx, __shfl_xor(mx, 32, 64));
        mx *= sc2;
        const int resc = (mx - mrun) > 11.5f;
        const float mm = resc ? mx : mrun;
        const float fac = resc ? __builtin_amdgcn_exp2f(mrun - mm) : 1.0f;
        mrun = mm;
        float p[4][4];
        float sum = 0.f;
#pragma unroll
        for (int n = 0; n < 4; ++n)
#pragma unroll
            for (int r = 0; r < 4; ++r) {
                float pv = __builtin_amdgcn_exp2f(sv[n][r] * sc2 - mm);
                p[n][r] = pv;
                sum += pv;
            }
        sum += __shfl_xor(sum, 16, 64);
        sum += __shfl_xor(sum, 32, 64);
        lrun = lrun * fac + sum;
        if (__any(resc)) {
#pragma unroll
            for (int r = 0; r < 4; ++r) {
                float fr = __shfl(fac, 4 * lg + r, 64);
#pragma unroll
                for (int nd = 0; nd < 8; ++nd) acc[nd][r] *= fr;
            }
        }

        // P -> LDS: 4 consecutive j per lane -> one b64 write per n
#pragma unroll
        for (int n = 0; n < 4; ++n) {
            uint2 wpk;
            wpk.x = cvt_pk_bf16(p[n][0], p[n][1]);
            wpk.y = cvt_pk_bf16(p[n][2], p[n][3]);
            int addr = prow * 128 + ((32 * n + 8 * lg) ^ pswz);
            *(uint2*)((char*)lP + addr) = wpk;
        }

        // O += P V (V frags from registers)
        __builtin_amdgcn_s_setprio(1);
#pragma unroll
        for (int kk2 = 0; kk2 < 2; ++kk2) {
            int pa_off = prow * 128 + ((64 * kk2 + 16 * lg) ^ pswz);
            s16x8 pa = *(const s16x8*)((const char*)lP + pa_off);
#pragma unroll
            for (int nd = 0; nd < 8; ++nd)
                acc[nd] = __builtin_amdgcn_mfma_f32_16x16x32_bf16(pa, vf[nd * 2 + kk2], acc[nd], 0, 0, 0);
        }
        __builtin_amdgcn_s_setprio(0);
    }

    if (mode == 0) {
        // normalize + write bf16; l for acc-row q=4lg+r lives at lane 4lg+r
#pragma unroll
        for (int r = 0; r < 4; ++r) {
            float invl = 1.0f / __shfl(lrun, 4 * lg + r, 64);
            int row = qrow0 + 4 * lg + r;
#pragma unroll
            for (int nd = 0; nd < 8; ++nd)
                ob[(size_t)row * DIM + head * HD + nd * 16 + lr] = f2b(acc[nd][r] * invl);
        }
    } else {
        const int pair = (head * 21 + (qt - 21)) * 2 + (mode - 1);
        float* Op = Opart + (size_t)pair * (64 * 128);
#pragma unroll
        for (int r = 0; r < 4; ++r) {
            int rowl = wid * 16 + 4 * lg + r;
#pragma unroll
            for (int nd = 0; nd < 8; ++nd)
                Op[rowl * 128 + nd * 16 + lr] = acc[nd][r];
        }
        if (lg == 0) {
            float2 ml; ml.x = mrun; ml.y = lrun;
            ((float2*)mlp)[(size_t)pair * 64 + wid * 16 + lr] = ml;
        }
    }
#undef STAGE
}

// ------------------------------------------------- LSE merge of 2 partials
__global__ __launch_bounds__(256) void k_merge(const float* __restrict__ Opart,
                                               const float* __restrict__ mlp,
                                               u16* __restrict__ ob) {
    const int b = blockIdx.x;
    const int qt2 = b % 21, head = b / 21;
    const int pair = head * 21 + qt2;
    const float* O0 = Opart + (size_t)pair * 2 * 8192;
    const float* O1 = O0 + 8192;
    const int tid = threadIdx.x;
    const int row = tid >> 2, cs = (tid & 3) * 32;
    float2 a = ((const float2*)mlp)[(size_t)pair * 2 * 64 + row];
    float2 c = ((const float2*)mlp)[(size_t)(pair * 2 + 1) * 64 + row];
    float M = fmaxf(a.x, c.x);
    float w0 = exp2f(a.x - M), w1 = exp2f(c.x - M);
    float inv = 1.0f / (w0 * a.y + w1 * c.y);
    w0 *= inv; w1 *= inv;
    const int rowg = BLK_TOK + qt2 * 64 + row;
    u32* orow = (u32*)(ob + (size_t)rowg * DIM + head * HD + cs);
    const float4* p0 = (const float4*)(O0 + row * 128 + cs);
    const float4* p1 = (const float4*)(O1 + row * 128 + cs);
#pragma unroll
    for (int u = 0; u < 8; ++u) {
        float4 x0 = p0[u], x1 = p1[u];
        float o0 = x0.x * w0 + x1.x * w1;
        float o1 = x0.y * w0 + x1.y * w1;
        float o2 = x0.z * w0 + x1.z * w1;
        float o3 = x0.w * w0 + x1.w * w1;
        orow[u * 2]     = (u32)f2b(o0) | ((u32)f2b(o1) << 16);
        orow[u * 2 + 1] = (u32)f2b(o2) | ((u32)f2b(o3) << 16);
    }
}

// ---------------------------------------------------------------- launcher
extern "C" void kernel_launch(void* const* d_in, const int* in_sizes, int n_in,
                              void* d_out, int out_size, void* d_ws, size_t ws_size,
                              hipStream_t stream) {
    const float* x     = (const float*)d_in[0];
    const float* freqs = (const float*)d_in[3];
    const float* Wq    = (const float*)d_in[4];
    const float* bq    = (const float*)d_in[5];
    const float* Wk    = (const float*)d_in[6];
    const float* bk    = (const float*)d_in[7];
    const float* Wv    = (const float*)d_in[8];
    const float* bv    = (const float*)d_in[9];
    const float* Wo    = (const float*)d_in[10];
    const float* bo    = (const float*)d_in[11];
    const float* gq    = (const float*)d_in[12];
    const float* gk    = (const float*)d_in[13];

    const size_t LD = (size_t)L_SEQ * DIM;   // elements
    u16* wt_all  = (u16*)d_ws;                         // 4 * DIM*DIM bf16
    u16* xb      = wt_all + (size_t)4 * DIM * DIM;     // L*DIM
    u16* pre_all = xb + LD;                            // 3 * L*DIM (q,k,v pre)
    u16* qh      = pre_all + 3 * LD;                   // [h][i][d]
    u16* kh2     = qh + LD;
    u16* vt      = kh2 + LD;
    u16* ob      = vt + LD;                            // attn out bf16 [i][c]
    // partials alias pre_all (dead once attention starts): 16.8 MB < 24.8 MB
    float* Opart = (float*)pre_all;                    // 12*21*2*64*128 f32
    float* mlp   = Opart + (size_t)12 * 21 * 2 * 64 * 128;

    k_cvt_x<<<2016, 256, 0, stream>>>(x, xb, (int)(LD / 4));
    k_trans_w<<<dim3(24, 24, 4), 256, 0, stream>>>(Wq, Wk, Wv, Wo, wt_all);
    k_gemm<0><<<dim3(12, 21, 3), 256, 0, stream>>>(xb, wt_all, bq, bk, bv, pre_all);
    k_norm_rope<<<dim3(L_SEQ, 2), 256, 0, stream>>>(pre_all, gq, gk, freqs, qh, kh2);
    k_vtrans<<<dim3(42, 2, NH), 256, 0, stream>>>(pre_all + 2 * LD, vt);
    k_attn<<<dim3(756), 256, 0, stream>>>(qh, kh2, vt, ob, Opart, mlp);
    k_merge<<<dim3(252), 256, 0, stream>>>(Opart, mlp, ob);
    k_gemm<1><<<dim3(12, 21, 1), 256, 0, stream>>>(ob, wt_all + (size_t)3 * DIM * DIM, bo, bo, bo, d_out);
}

// Round 7
// 200.620 us; speedup vs baseline: 1.2264x; 1.2264x over previous
//
#include <hip/hip_runtime.h>

#define L_SEQ 2688
#define DIM   1536
#define NH    12
#define HD    128
#define BLK_TOK 1344   // 3*H*W
#define HW_   448      // H*W
#define W_    28

typedef unsigned short u16;
typedef unsigned int   u32;
typedef __attribute__((ext_vector_type(4))) float f32x4;
typedef __attribute__((ext_vector_type(8))) short s16x8;

__device__ __forceinline__ u16 f2b(float f) {
    u32 u = __builtin_bit_cast(u32, f);
    return (u16)((u + 0x7FFFu + ((u >> 16) & 1u)) >> 16);   // RNE
}
__device__ __forceinline__ float b2f(u16 b) {
    return __builtin_bit_cast(float, (u32)b << 16);
}
__device__ __forceinline__ u32 cvt_pk_bf16(float lo, float hi) {
    u32 r;
    asm("v_cvt_pk_bf16_f32 %0, %1, %2" : "=v"(r) : "v"(lo), "v"(hi));
    return r;
}

// ---------------------------------------------------------------- x -> bf16
__global__ __launch_bounds__(256) void k_cvt_x(const float* __restrict__ x,
                                               u16* __restrict__ xb, int n4) {
    int i = blockIdx.x * 256 + threadIdx.x;
    int stride = gridDim.x * 256;
    for (; i < n4; i += stride) {
        float4 v = ((const float4*)x)[i];
        ushort4 o;
        o.x = f2b(v.x); o.y = f2b(v.y); o.z = f2b(v.z); o.w = f2b(v.w);
        ((ushort4*)xb)[i] = o;
    }
}

// ------------------------------------- W (f32 [K][N]) -> Wt (bf16 [N][K])
__global__ __launch_bounds__(256) void k_trans_w(const float* __restrict__ w0,
                                                 const float* __restrict__ w1,
                                                 const float* __restrict__ w2,
                                                 const float* __restrict__ w3,
                                                 u16* __restrict__ wt_all) {
    const float* w = blockIdx.z == 0 ? w0 : blockIdx.z == 1 ? w1 : blockIdx.z == 2 ? w2 : w3;
    u16* wt = wt_all + (size_t)blockIdx.z * DIM * DIM;
    __shared__ float t[64][65];
    const int k0 = blockIdx.y * 64, n0 = blockIdx.x * 64;
    const int c = threadIdx.x & 63, rg = threadIdx.x >> 6;
#pragma unroll
    for (int it = 0; it < 16; ++it) {
        int r = rg * 16 + it;
        t[r][c] = w[(size_t)(k0 + r) * DIM + n0 + c];
    }
    __syncthreads();
#pragma unroll
    for (int it = 0; it < 16; ++it) {
        int r = rg * 16 + it;
        wt[(size_t)(n0 + r) * DIM + k0 + c] = f2b(t[c][r]);
    }
}

// ------------------------------------------------- GEMM: C = A*Bt^T + bias
template<int OUTF>
__global__ __launch_bounds__(256, 2) void k_gemm(const u16* __restrict__ A,
                                                 const u16* __restrict__ Bt_all,
                                                 const float* __restrict__ b0,
                                                 const float* __restrict__ b1,
                                                 const float* __restrict__ b2,
                                                 void* __restrict__ out_all) {
    const int z = blockIdx.z;
    const u16* Bt = Bt_all + (size_t)z * DIM * DIM;
    const float* bias = z == 0 ? b0 : z == 1 ? b1 : b2;

    __shared__ u16 lA[128 * 32];
    __shared__ u16 lB[128 * 32];
    const int tid = threadIdx.x, lane = tid & 63, wid = tid >> 6;
    const int wm = wid >> 1, wn = wid & 1;
    const int bm = blockIdx.y, bn = blockIdx.x;
    const int lr = lane & 15, lg = lane >> 4;

    f32x4 acc[4][4] = {};

    for (int kt = 0; kt < DIM / 32; ++kt) {
#pragma unroll
        for (int i = 0; i < 2; ++i) {
            int s = wid * 128 + i * 64 + lane;        // 16B slot id
            int row = s >> 2, c16 = s & 3;            // 4 slots per 32-elem row
            const u16* ga = A + (size_t)(bm * 128 + row) * DIM + kt * 32 + c16 * 8;
            __builtin_amdgcn_global_load_lds(
                (const __attribute__((address_space(1))) u32*)ga,
                (__attribute__((address_space(3))) u32*)&lA[(wid * 128 + i * 64) * 8],
                16, 0, 0);
            const u16* gb = Bt + (size_t)(bn * 128 + row) * DIM + kt * 32 + c16 * 8;
            __builtin_amdgcn_global_load_lds(
                (const __attribute__((address_space(1))) u32*)gb,
                (__attribute__((address_space(3))) u32*)&lB[(wid * 128 + i * 64) * 8],
                16, 0, 0);
        }
        __syncthreads();
        s16x8 af[4], bf[4];
#pragma unroll
        for (int m = 0; m < 4; ++m)
            af[m] = *(const s16x8*)&lA[(wm * 64 + m * 16 + lr) * 32 + lg * 8];
#pragma unroll
        for (int n = 0; n < 4; ++n)
            bf[n] = *(const s16x8*)&lB[(wn * 64 + n * 16 + lr) * 32 + lg * 8];
#pragma unroll
        for (int m = 0; m < 4; ++m)
#pragma unroll
            for (int n = 0; n < 4; ++n)
                acc[m][n] = __builtin_amdgcn_mfma_f32_16x16x32_bf16(af[m], bf[n], acc[m][n], 0, 0, 0);
        __syncthreads();
    }
#pragma unroll
    for (int n = 0; n < 4; ++n) {
        int col = bn * 128 + wn * 64 + n * 16 + lr;
        float bv = bias[col];
#pragma unroll
        for (int m = 0; m < 4; ++m) {
            int row0 = bm * 128 + wm * 64 + m * 16 + lg * 4;
#pragma unroll
            for (int r = 0; r < 4; ++r) {
                float v = acc[m][n][r] + bv;
                if (OUTF)
                    ((float*)out_all)[(size_t)(row0 + r) * DIM + col] = v;
                else
                    ((u16*)out_all)[(size_t)z * L_SEQ * DIM + (size_t)(row0 + r) * DIM + col] = f2b(v);
            }
        }
    }
}

// ---------------- RMSNorm(row of 1536) + RoPE -> [h][i][d]; y selects q/k
__global__ __launch_bounds__(256) void k_norm_rope(const u16* __restrict__ pre_all,
                                                   const float* __restrict__ gq,
                                                   const float* __restrict__ gk,
                                                   const float* __restrict__ freqs,
                                                   u16* __restrict__ qh,
                                                   u16* __restrict__ kh) {
    const int which = blockIdx.y;
    const u16* pre = pre_all + (size_t)which * L_SEQ * DIM;
    const float* g = which ? gk : gq;
    u16* outh = which ? kh : qh;

    const int i = blockIdx.x;
    const int t = threadIdx.x;
    const u32* prow = (const u32*)(pre + (size_t)i * DIM);  // 768 bf16 pairs

    float re[3], im[3];
    float ss = 0.f;
#pragma unroll
    for (int a = 0; a < 3; ++a) {
        u32 p = prow[t + a * 256];
        float x = b2f((u16)(p & 0xFFFFu)), y = b2f((u16)(p >> 16));
        re[a] = x; im[a] = y;
        ss += x * x + y * y;
    }
#pragma unroll
    for (int o = 32; o > 0; o >>= 1) ss += __shfl_down(ss, o, 64);
    __shared__ float sred[4];
    if ((t & 63) == 0) sred[t >> 6] = ss;
    __syncthreads();
    float rms = rsqrtf((sred[0] + sred[1] + sred[2] + sred[3]) * (1.0f / DIM) + 1e-6f);

    const int f = i / HW_;
    const int rem = i - f * HW_;
    const int hp = rem / W_;
    const int wp = rem - hp * W_;
#pragma unroll
    for (int a = 0; a < 3; ++a) {
        int j = t + a * 256;         // pair index in row: head h = j>>6, pj = j&63
        int h = j >> 6, pj = j & 63;
        float2 gg = ((const float2*)g)[j];
        float x = re[a] * rms * gg.x;
        float y = im[a] * rms * gg.y;
        int ridx = pj < 22 ? f : (pj < 43 ? hp : wp);
        float2 cs = ((const float2*)freqs)[ridx * 64 + pj];
        float ore = x * cs.x - y * cs.y;
        float oim = x * cs.y + y * cs.x;
        u32 o = (u32)f2b(ore) | ((u32)f2b(oim) << 16);
        ((u32*)outh)[(size_t)h * (L_SEQ * 64) + (size_t)i * 64 + pj] = o;
    }
}

// ------------------------------------------ v [i][h*128+d] -> vt [h][d][i]
__global__ __launch_bounds__(256) void k_vtrans(const u16* __restrict__ vpre,
                                                u16* __restrict__ vt) {
    const int i0 = blockIdx.x * 64, d0 = blockIdx.y * 64, h = blockIdx.z;
    __shared__ u16 t[64][68];
    const int c = threadIdx.x & 63, rg = threadIdx.x >> 6;
#pragma unroll
    for (int it = 0; it < 16; ++it) {
        int r = rg * 16 + it;
        t[r][c] = vpre[(size_t)(i0 + r) * DIM + h * HD + d0 + c];
    }
    __syncthreads();
#pragma unroll
    for (int it = 0; it < 16; ++it) {
        int r = rg * 16 + it;  // d index
        vt[(size_t)h * (HD * L_SEQ) + (size_t)(d0 + r) * L_SEQ + i0 + c] = t[c][r];
    }
}

// ----------------------------------------------------- flash attention v7
// 756 jobs (v3 worklist). 128 thr = 2 waves x 32 q-rows (2 groups of 16).
// K,V single-buffered LDS (40 KB -> ~3 independent blocks/CU) staged via
// global_load_lds; each K/V fragment read from LDS feeds TWO MFMAs
// (register reuse across q-groups) -> LDS read traffic per unit work halves
// vs v3. Swapped QK^T; split-KV + LSE merge unchanged.
__global__ __launch_bounds__(128) void k_attn(const u16* __restrict__ qh,
                                              const u16* __restrict__ kh,
                                              const u16* __restrict__ vt,
                                              u16* __restrict__ ob,
                                              float* __restrict__ Opart,
                                              float* __restrict__ mlp) {
    __shared__ u16 lK[64 * 128];   // [j][d], slot-XOR swizzled
    __shared__ u16 lV[128 * 64];   // [d][j], slot-XOR swizzled
    __shared__ u16 lP[64 * 64];    // [qrow][j], wave-private rows

    // bijective XCD swizzle: 756 blocks, consecutive ids round-robin XCDs
    const int flat = blockIdx.x;
    const int xcd = flat & 7, idx = flat >> 3;
    const int work = (xcd < 4) ? (xcd * 95 + idx) : (380 + (xcd - 4) * 94 + idx);
    const int head = work / 63;
    const int bx = work - head * 63;
    int qt, kv0, mode;
    if (bx < 21)      { qt = bx;      kv0 = 0;  mode = 0; }
    else if (bx < 42) { qt = bx;      kv0 = 0;  mode = 1; }
    else              { qt = bx - 21; kv0 = 21; mode = 2; }

    const int tid = threadIdx.x, lane = tid & 63, w = tid >> 6;   // wave 0/1
    const int lr = lane & 15, lg = lane >> 4;
    const size_t hOff = (size_t)head * ((size_t)L_SEQ * HD);
    const u16* Kh = kh + hOff;
    const u16* Vh = vt + hOff;
    const int qrow0 = qt * 64 + w * 32;

    // Q fragments (B-operand), 2 groups of 16 rows
    s16x8 aq[2][4];
#pragma unroll
    for (int g = 0; g < 2; ++g)
#pragma unroll
        for (int kk = 0; kk < 4; ++kk)
            aq[g][kk] = *(const s16x8*)&qh[hOff + (size_t)(qrow0 + 16 * g + lr) * HD + kk * 32 + lg * 8];

    // ---- staging pointers (pre-swizzled global source, linear LDS dest)
    // K: issue i covers rows i*8 + rh (rh = tid>>4), slot ck = tid&15,
    //    source col 8*(ck ^ (j&15)) with j&15 = (i&1)*8 + rh.
    const int rh = tid >> 4, ck = tid & 15;
    const u16* kapA = Kh + (size_t)(kv0 * 64 + rh) * HD + 8 * (ck ^ rh);
    const u16* kapB = Kh + (size_t)(kv0 * 64 + 8 + rh) * HD + 8 * (ck ^ (8 + rh));
    // V: issue i covers d = i*16 + rv (rv = tid>>3), slot cvv = tid&7,
    //    source col 8*(cvv ^ (d&7)) with d&7 = rv&7.
    const int rv = tid >> 3, cvv = tid & 7;
    const u16* vap = Vh + (size_t)rv * L_SEQ + kv0 * 64 + 8 * (cvv ^ (rv & 7));

#define STAGE(T)                                                                     \
    {                                                                                \
        _Pragma("unroll")                                                            \
        for (int i = 0; i < 8; ++i) {                                                \
            const u16* src = ((i & 1) ? kapB : kapA) + (size_t)(i >> 1) * 16 * HD +  \
                             (size_t)(T) * 8192;                                     \
            __builtin_amdgcn_global_load_lds(                                        \
                (const __attribute__((address_space(1))) u32*)src,                   \
                (__attribute__((address_space(3))) u32*)((char*)lK + i * 2048 + tid * 16), \
                16, 0, 0);                                                           \
        }                                                                            \
        _Pragma("unroll")                                                            \
        for (int i = 0; i < 8; ++i) {                                                \
            const u16* src = vap + (size_t)i * 16 * L_SEQ + (T) * 64;                \
            __builtin_amdgcn_global_load_lds(                                        \
                (const __attribute__((address_space(1))) u32*)src,                   \
                (__attribute__((address_space(3))) u32*)((char*)lV + i * 2048 + tid * 16), \
                16, 0, 0);                                                           \
        }                                                                            \
    }

    f32x4 acc[2][8] = {};
    float mrun[2], lrun[2];
#pragma unroll
    for (int g = 0; g < 2; ++g) { mrun[g] = -1e30f; lrun[g] = 0.f; }
    const float sc2 = 0.12751739646917983f;  // 1/sqrt(128) * log2(e)
    const int pswz = (lr & 7) << 4;

    for (int t = 0; t < 21; ++t) {
        __syncthreads();                 // all waves done reading tile t-1
        STAGE(t);
        __syncthreads();                 // gload_lds drained (vmcnt0 + barrier)

        // ---- S^T = K Q^T for both q-groups; each kf read feeds 2 MFMAs
        f32x4 sv[2][4] = {};
        __builtin_amdgcn_s_setprio(1);
#pragma unroll
        for (int n = 0; n < 4; ++n)
#pragma unroll
            for (int kk = 0; kk < 4; ++kk) {
                int off = (16 * n + lr) * 256 + ((64 * kk + 16 * lg) ^ (lr << 4));
                s16x8 kf = *(const s16x8*)((const char*)lK + off);
                sv[0][n] = __builtin_amdgcn_mfma_f32_16x16x32_bf16(kf, aq[0][kk], sv[0][n], 0, 0, 0);
                sv[1][n] = __builtin_amdgcn_mfma_f32_16x16x32_bf16(kf, aq[1][kk], sv[1][n], 0, 0, 0);
            }
        __builtin_amdgcn_s_setprio(0);

        // ---- online softmax per group (row q=16g+lr; 2 shuffles per reduce)
        float fac[2];
        int anyr = 0;
#pragma unroll
        for (int g = 0; g < 2; ++g) {
            float mx = sv[g][0][0];
#pragma unroll
            for (int n = 0; n < 4; ++n)
                mx = fmaxf(mx, fmaxf(fmaxf(sv[g][n][0], sv[g][n][1]),
                                     fmaxf(sv[g][n][2], sv[g][n][3])));
            mx = fmaxf(mx, __shfl_xor(mx, 16, 64));
            mx = fmaxf(mx, __shfl_xor(mx, 32, 64));
            mx *= sc2;
            const int resc = (mx - mrun[g]) > 11.5f;
            const float mm = resc ? mx : mrun[g];
            fac[g] = resc ? __builtin_amdgcn_exp2f(mrun[g] - mm) : 1.0f;
            mrun[g] = mm;
            anyr |= resc;
            float sum = 0.f;
#pragma unroll
            for (int n = 0; n < 4; ++n)
#pragma unroll
                for (int r = 0; r < 4; ++r) {
                    float pv = __builtin_amdgcn_exp2f(sv[g][n][r] * sc2 - mm);
                    sv[g][n][r] = pv;
                    sum += pv;
                }
            sum += __shfl_xor(sum, 16, 64);
            sum += __shfl_xor(sum, 32, 64);
            lrun[g] = lrun[g] * fac[g] + sum;
        }
        if (__any(anyr)) {
#pragma unroll
            for (int g = 0; g < 2; ++g)
#pragma unroll
                for (int r = 0; r < 4; ++r) {
                    float fr = __shfl(fac[g], 4 * lg + r, 64);
#pragma unroll
                    for (int nd = 0; nd < 8; ++nd) acc[g][nd][r] *= fr;
                }
        }

        // ---- P -> LDS (bf16, swizzled, wave-private rows)
#pragma unroll
        for (int g = 0; g < 2; ++g) {
            int row = w * 32 + 16 * g + lr;
#pragma unroll
            for (int n = 0; n < 4; ++n) {
                uint2 wpk;
                wpk.x = cvt_pk_bf16(sv[g][n][0], sv[g][n][1]);
                wpk.y = cvt_pk_bf16(sv[g][n][2], sv[g][n][3]);
                int addr = row * 128 + ((32 * n + 8 * lg) ^ pswz);
                *(uint2*)((char*)lP + addr) = wpk;
            }
        }

        // ---- O += P V ; each V fragment read feeds 2 MFMAs
        __builtin_amdgcn_s_setprio(1);
#pragma unroll
        for (int kk2 = 0; kk2 < 2; ++kk2) {
            int cb = (64 * kk2 + 16 * lg);
            s16x8 pa0 = *(const s16x8*)((const char*)lP + (w * 32 + lr) * 128 + (cb ^ pswz));
            s16x8 pa1 = *(const s16x8*)((const char*)lP + (w * 32 + 16 + lr) * 128 + (cb ^ pswz));
#pragma unroll
            for (int nd = 0; nd < 8; ++nd) {
                int va = (16 * nd + lr) * 128 + (cb ^ ((lr & 7) << 4));
                s16x8 bvv = *(const s16x8*)((const char*)lV + va);
                acc[0][nd] = __builtin_amdgcn_mfma_f32_16x16x32_bf16(pa0, bvv, acc[0][nd], 0, 0, 0);
                acc[1][nd] = __builtin_amdgcn_mfma_f32_16x16x32_bf16(pa1, bvv, acc[1][nd], 0, 0, 0);
            }
        }
        __builtin_amdgcn_s_setprio(0);
    }

    if (mode == 0) {
#pragma unroll
        for (int g = 0; g < 2; ++g)
#pragma unroll
            for (int r = 0; r < 4; ++r) {
                float invl = 1.0f / __shfl(lrun[g], 4 * lg + r, 64);
                int row = qrow0 + 16 * g + 4 * lg + r;
#pragma unroll
                for (int nd = 0; nd < 8; ++nd)
                    ob[(size_t)row * DIM + head * HD + nd * 16 + lr] = f2b(acc[g][nd][r] * invl);
            }
    } else {
        const int pair = (head * 21 + (qt - 21)) * 2 + (mode - 1);
        float* Op = Opart + (size_t)pair * (64 * 128);
#pragma unroll
        for (int g = 0; g < 2; ++g)
#pragma unroll
            for (int r = 0; r < 4; ++r) {
                int rowl = w * 32 + 16 * g + 4 * lg + r;
#pragma unroll
                for (int nd = 0; nd < 8; ++nd)
                    Op[rowl * 128 + nd * 16 + lr] = acc[g][nd][r];
            }
        if (lg == 0) {
#pragma unroll
            for (int g = 0; g < 2; ++g) {
                float2 ml; ml.x = mrun[g]; ml.y = lrun[g];
                ((float2*)mlp)[(size_t)pair * 64 + w * 32 + 16 * g + lr] = ml;
            }
        }
    }
#undef STAGE
}

// ------------------------------------------------- LSE merge of 2 partials
__global__ __launch_bounds__(256) void k_merge(const float* __restrict__ Opart,
                                               const float* __restrict__ mlp,
                                               u16* __restrict__ ob) {
    const int b = blockIdx.x;
    const int qt2 = b % 21, head = b / 21;
    const int pair = head * 21 + qt2;
    const float* O0 = Opart + (size_t)pair * 2 * 8192;
    const float* O1 = O0 + 8192;
    const int tid = threadIdx.x;
    const int row = tid >> 2, cs = (tid & 3) * 32;
    float2 a = ((const float2*)mlp)[(size_t)pair * 2 * 64 + row];
    float2 c = ((const float2*)mlp)[(size_t)(pair * 2 + 1) * 64 + row];
    float M = fmaxf(a.x, c.x);
    float w0 = exp2f(a.x - M), w1 = exp2f(c.x - M);
    float inv = 1.0f / (w0 * a.y + w1 * c.y);
    w0 *= inv; w1 *= inv;
    const int rowg = BLK_TOK + qt2 * 64 + row;
    u32* orow = (u32*)(ob + (size_t)rowg * DIM + head * HD + cs);
    const float4* p0 = (const float4*)(O0 + row * 128 + cs);
    const float4* p1 = (const float4*)(O1 + row * 128 + cs);
#pragma unroll
    for (int u = 0; u < 8; ++u) {
        float4 x0 = p0[u], x1 = p1[u];
        float o0 = x0.x * w0 + x1.x * w1;
        float o1 = x0.y * w0 + x1.y * w1;
        float o2 = x0.z * w0 + x1.z * w1;
        float o3 = x0.w * w0 + x1.w * w1;
        orow[u * 2]     = (u32)f2b(o0) | ((u32)f2b(o1) << 16);
        orow[u * 2 + 1] = (u32)f2b(o2) | ((u32)f2b(o3) << 16);
    }
}

// ---------------------------------------------------------------- launcher
extern "C" void kernel_launch(void* const* d_in, const int* in_sizes, int n_in,
                              void* d_out, int out_size, void* d_ws, size_t ws_size,
                              hipStream_t stream) {
    const float* x     = (const float*)d_in[0];
    const float* freqs = (const float*)d_in[3];
    const float* Wq    = (const float*)d_in[4];
    const float* bq    = (const float*)d_in[5];
    const float* Wk    = (const float*)d_in[6];
    const float* bk    = (const float*)d_in[7];
    const float* Wv    = (const float*)d_in[8];
    const float* bv    = (const float*)d_in[9];
    const float* Wo    = (const float*)d_in[10];
    const float* bo    = (const float*)d_in[11];
    const float* gq    = (const float*)d_in[12];
    const float* gk    = (const float*)d_in[13];

    const size_t LD = (size_t)L_SEQ * DIM;   // elements
    u16* wt_all  = (u16*)d_ws;                         // 4 * DIM*DIM bf16
    u16* xb      = wt_all + (size_t)4 * DIM * DIM;     // L*DIM
    u16* pre_all = xb + LD;                            // 3 * L*DIM (q,k,v pre)
    u16* qh      = pre_all + 3 * LD;                   // [h][i][d]
    u16* kh2     = qh + LD;
    u16* vt      = kh2 + LD;
    u16* ob      = vt + LD;                            // attn out bf16 [i][c]
    // partials alias pre_all (dead once attention starts): 16.8 MB < 24.8 MB
    float* Opart = (float*)pre_all;                    // 12*21*2*64*128 f32
    float* mlp   = Opart + (size_t)12 * 21 * 2 * 64 * 128;

    k_cvt_x<<<2016, 256, 0, stream>>>(x, xb, (int)(LD / 4));
    k_trans_w<<<dim3(24, 24, 4), 256, 0, stream>>>(Wq, Wk, Wv, Wo, wt_all);
    k_gemm<0><<<dim3(12, 21, 3), 256, 0, stream>>>(xb, wt_all, bq, bk, bv, pre_all);
    k_norm_rope<<<dim3(L_SEQ, 2), 256, 0, stream>>>(pre_all, gq, gk, freqs, qh, kh2);
    k_vtrans<<<dim3(42, 2, NH), 256, 0, stream>>>(pre_all + 2 * LD, vt);
    k_attn<<<dim3(756), 128, 0, stream>>>(qh, kh2, vt, ob, Opart, mlp);
    k_merge<<<dim3(252), 256, 0, stream>>>(Opart, mlp, ob);
    k_gemm<1><<<dim3(12, 21, 1), 256, 0, stream>>>(ob, wt_all + (size_t)3 * DIM * DIM, bo, bo, bo, d_out);
}

// Round 8
// 173.708 us; speedup vs baseline: 1.4164x; 1.1549x over previous
//
#include <hip/hip_runtime.h>

#define L_SEQ 2688
#define DIM   1536
#define NH    12
#define HD    128
#define BLK_TOK 1344   // 3*H*W
#define HW_   448      // H*W
#define W_    28

typedef unsigned short u16;
typedef unsigned int   u32;
typedef __attribute__((ext_vector_type(4))) float f32x4;
typedef __attribute__((ext_vector_type(16))) float f32x16;
typedef __attribute__((ext_vector_type(8))) short s16x8;
typedef __attribute__((ext_vector_type(2))) int i32x2;
typedef __attribute__((ext_vector_type(4))) u32 u32x4;

__device__ __forceinline__ u16 f2b(float f) {
    u32 u = __builtin_bit_cast(u32, f);
    return (u16)((u + 0x7FFFu + ((u >> 16) & 1u)) >> 16);   // RNE
}
__device__ __forceinline__ float b2f(u16 b) {
    return __builtin_bit_cast(float, (u32)b << 16);
}
__device__ __forceinline__ u32 cvt_pk_bf16(float lo, float hi) {
    u32 r;
    asm("v_cvt_pk_bf16_f32 %0, %1, %2" : "=v"(r) : "v"(lo), "v"(hi));
    return r;
}

// ---------------------------------------------------------------- x -> bf16
__global__ __launch_bounds__(256) void k_cvt_x(const float* __restrict__ x,
                                               u16* __restrict__ xb, int n4) {
    int i = blockIdx.x * 256 + threadIdx.x;
    int stride = gridDim.x * 256;
    for (; i < n4; i += stride) {
        float4 v = ((const float4*)x)[i];
        ushort4 o;
        o.x = f2b(v.x); o.y = f2b(v.y); o.z = f2b(v.z); o.w = f2b(v.w);
        ((ushort4*)xb)[i] = o;
    }
}

// ------------------------------------- W (f32 [K][N]) -> Wt (bf16 [N][K])
__global__ __launch_bounds__(256) void k_trans_w(const float* __restrict__ w0,
                                                 const float* __restrict__ w1,
                                                 const float* __restrict__ w2,
                                                 const float* __restrict__ w3,
                                                 u16* __restrict__ wt_all) {
    const float* w = blockIdx.z == 0 ? w0 : blockIdx.z == 1 ? w1 : blockIdx.z == 2 ? w2 : w3;
    u16* wt = wt_all + (size_t)blockIdx.z * DIM * DIM;
    __shared__ float t[64][65];
    const int k0 = blockIdx.y * 64, n0 = blockIdx.x * 64;
    const int c = threadIdx.x & 63, rg = threadIdx.x >> 6;
#pragma unroll
    for (int it = 0; it < 16; ++it) {
        int r = rg * 16 + it;
        t[r][c] = w[(size_t)(k0 + r) * DIM + n0 + c];
    }
    __syncthreads();
#pragma unroll
    for (int it = 0; it < 16; ++it) {
        int r = rg * 16 + it;
        wt[(size_t)(n0 + r) * DIM + k0 + c] = f2b(t[c][r]);
    }
}

// ------------------------------------------------- GEMM: C = A*Bt^T + bias
template<int OUTF>
__global__ __launch_bounds__(256, 2) void k_gemm(const u16* __restrict__ A,
                                                 const u16* __restrict__ Bt_all,
                                                 const float* __restrict__ b0,
                                                 const float* __restrict__ b1,
                                                 const float* __restrict__ b2,
                                                 void* __restrict__ out_all) {
    const int z = blockIdx.z;
    const u16* Bt = Bt_all + (size_t)z * DIM * DIM;
    const float* bias = z == 0 ? b0 : z == 1 ? b1 : b2;

    __shared__ u16 lA[128 * 32];
    __shared__ u16 lB[128 * 32];
    const int tid = threadIdx.x, lane = tid & 63, wid = tid >> 6;
    const int wm = wid >> 1, wn = wid & 1;
    const int bm = blockIdx.y, bn = blockIdx.x;
    const int lr = lane & 15, lg = lane >> 4;

    f32x4 acc[4][4] = {};

    for (int kt = 0; kt < DIM / 32; ++kt) {
#pragma unroll
        for (int i = 0; i < 2; ++i) {
            int s = wid * 128 + i * 64 + lane;        // 16B slot id
            int row = s >> 2, c16 = s & 3;            // 4 slots per 32-elem row
            const u16* ga = A + (size_t)(bm * 128 + row) * DIM + kt * 32 + c16 * 8;
            __builtin_amdgcn_global_load_lds(
                (const __attribute__((address_space(1))) u32*)ga,
                (__attribute__((address_space(3))) u32*)&lA[(wid * 128 + i * 64) * 8],
                16, 0, 0);
            const u16* gb = Bt + (size_t)(bn * 128 + row) * DIM + kt * 32 + c16 * 8;
            __builtin_amdgcn_global_load_lds(
                (const __attribute__((address_space(1))) u32*)gb,
                (__attribute__((address_space(3))) u32*)&lB[(wid * 128 + i * 64) * 8],
                16, 0, 0);
        }
        __syncthreads();
        s16x8 af[4], bf[4];
#pragma unroll
        for (int m = 0; m < 4; ++m)
            af[m] = *(const s16x8*)&lA[(wm * 64 + m * 16 + lr) * 32 + lg * 8];
#pragma unroll
        for (int n = 0; n < 4; ++n)
            bf[n] = *(const s16x8*)&lB[(wn * 64 + n * 16 + lr) * 32 + lg * 8];
#pragma unroll
        for (int m = 0; m < 4; ++m)
#pragma unroll
            for (int n = 0; n < 4; ++n)
                acc[m][n] = __builtin_amdgcn_mfma_f32_16x16x32_bf16(af[m], bf[n], acc[m][n], 0, 0, 0);
        __syncthreads();
    }
#pragma unroll
    for (int n = 0; n < 4; ++n) {
        int col = bn * 128 + wn * 64 + n * 16 + lr;
        float bv = bias[col];
#pragma unroll
        for (int m = 0; m < 4; ++m) {
            int row0 = bm * 128 + wm * 64 + m * 16 + lg * 4;
#pragma unroll
            for (int r = 0; r < 4; ++r) {
                float v = acc[m][n][r] + bv;
                if (OUTF)
                    ((float*)out_all)[(size_t)(row0 + r) * DIM + col] = v;
                else
                    ((u16*)out_all)[(size_t)z * L_SEQ * DIM + (size_t)(row0 + r) * DIM + col] = f2b(v);
            }
        }
    }
}

// ---------------- RMSNorm(row of 1536) + RoPE -> [h][i][d]; y selects q/k
__global__ __launch_bounds__(256) void k_norm_rope(const u16* __restrict__ pre_all,
                                                   const float* __restrict__ gq,
                                                   const float* __restrict__ gk,
                                                   const float* __restrict__ freqs,
                                                   u16* __restrict__ qh,
                                                   u16* __restrict__ kh) {
    const int which = blockIdx.y;
    const u16* pre = pre_all + (size_t)which * L_SEQ * DIM;
    const float* g = which ? gk : gq;
    u16* outh = which ? kh : qh;

    const int i = blockIdx.x;
    const int t = threadIdx.x;
    const u32* prow = (const u32*)(pre + (size_t)i * DIM);  // 768 bf16 pairs

    float re[3], im[3];
    float ss = 0.f;
#pragma unroll
    for (int a = 0; a < 3; ++a) {
        u32 p = prow[t + a * 256];
        float x = b2f((u16)(p & 0xFFFFu)), y = b2f((u16)(p >> 16));
        re[a] = x; im[a] = y;
        ss += x * x + y * y;
    }
#pragma unroll
    for (int o = 32; o > 0; o >>= 1) ss += __shfl_down(ss, o, 64);
    __shared__ float sred[4];
    if ((t & 63) == 0) sred[t >> 6] = ss;
    __syncthreads();
    float rms = rsqrtf((sred[0] + sred[1] + sred[2] + sred[3]) * (1.0f / DIM) + 1e-6f);

    const int f = i / HW_;
    const int rem = i - f * HW_;
    const int hp = rem / W_;
    const int wp = rem - hp * W_;
#pragma unroll
    for (int a = 0; a < 3; ++a) {
        int j = t + a * 256;         // pair index in row: head h = j>>6, pj = j&63
        int h = j >> 6, pj = j & 63;
        float2 gg = ((const float2*)g)[j];
        float x = re[a] * rms * gg.x;
        float y = im[a] * rms * gg.y;
        int ridx = pj < 22 ? f : (pj < 43 ? hp : wp);
        float2 cs = ((const float2*)freqs)[ridx * 64 + pj];
        float ore = x * cs.x - y * cs.y;
        float oim = x * cs.y + y * cs.x;
        u32 o = (u32)f2b(ore) | ((u32)f2b(oim) << 16);
        ((u32*)outh)[(size_t)h * (L_SEQ * 64) + (size_t)i * 64 + pj] = o;
    }
}

// ------------------------------------------ v [i][h*128+d] -> vt [h][d][i]
__global__ __launch_bounds__(256) void k_vtrans(const u16* __restrict__ vpre,
                                                u16* __restrict__ vt) {
    const int i0 = blockIdx.x * 64, d0 = blockIdx.y * 64, h = blockIdx.z;
    __shared__ u16 t[64][68];
    const int c = threadIdx.x & 63, rg = threadIdx.x >> 6;
#pragma unroll
    for (int it = 0; it < 16; ++it) {
        int r = rg * 16 + it;
        t[r][c] = vpre[(size_t)(i0 + r) * DIM + h * HD + d0 + c];
    }
    __syncthreads();
#pragma unroll
    for (int it = 0; it < 16; ++it) {
        int r = rg * 16 + it;  // d index
        vt[(size_t)h * (HD * L_SEQ) + (size_t)(d0 + r) * L_SEQ + i0 + c] = t[c][r];
    }
}

// ----------------------------------------------------- flash attention v8
// 756 jobs. 256 thr = 4 waves. Waves {0,1}: q-halves (32 rows each, lane owns
// one q-row via 32x32x16 MFMA col-layout) over EVEN KV tiles; waves {2,3}:
// same q-rows over ODD tiles. Per-pair single-buffered K+V LDS slots (64 KB),
// gload_lds staging (pre-swizzled sources). In-register P via cvt_pk +
// permlane32_swap (no P LDS round-trip). Pair LSE-merge in LDS at the end.
__global__ __launch_bounds__(256, 2) void k_attn(const u16* __restrict__ qh,
                                                 const u16* __restrict__ kh,
                                                 const u16* __restrict__ vt,
                                                 u16* __restrict__ ob,
                                                 float* __restrict__ Opart,
                                                 float* __restrict__ mlp) {
    __shared__ char lsm[2][32768];   // per-pair slot: [0,16K) K[64][128] swz, [16K,32K) V^T[128][64] swz

    // bijective XCD swizzle: 756 blocks, consecutive ids round-robin XCDs
    const int flat = blockIdx.x;
    const int xcd = flat & 7, idx = flat >> 3;
    const int work = (xcd < 4) ? (xcd * 95 + idx) : (380 + (xcd - 4) * 94 + idx);
    const int head = work / 63;
    const int bx = work - head * 63;
    int qt, kv0, mode;
    if (bx < 21)      { qt = bx;      kv0 = 0;  mode = 0; }
    else if (bx < 42) { qt = bx;      kv0 = 0;  mode = 1; }
    else              { qt = bx - 21; kv0 = 21; mode = 2; }

    const int tid = threadIdx.x, lane = tid & 63, w = tid >> 6;
    const int pairI = w >> 1;        // 0: even tiles, 1: odd tiles
    const int qhalf = w & 1;         // q-row half of the 64-row job
    const int q31 = lane & 31, hi = lane >> 5;
    const size_t hOff = (size_t)head * ((size_t)L_SEQ * HD);
    const u16* Kh = kh + hOff;
    const u16* Vh = vt + hOff;
    const int qrow0 = qt * 64 + qhalf * 32;

    // Q B-fragments (n=q31, k = 16kk + 8hi .. +8): 8 k-steps
    s16x8 aq[8];
#pragma unroll
    for (int kk = 0; kk < 8; ++kk)
        aq[kk] = *(const s16x8*)&qh[hOff + (size_t)(qrow0 + q31) * HD + kk * 16 + hi * 8];

    // staging decomposition (per-pair 128 threads)
    const int pt = tid & 127;
    const int rh = pt >> 4, ck = pt & 15;   // K: 8 issues, rows i*8+rh, slot ck
    const int rv = pt >> 3, cvv = pt & 7;   // V: 8 issues, d = i*16+rv, slot cvv
    char* slot = lsm[pairI];

    f32x16 acc[4] = {};
    float mrun = -1e30f, lrun = 0.f;
    const float sc2 = 0.12751739646917983f;  // 1/sqrt(128) * log2(e)

    for (int it = 0; it < 11; ++it) {
        const int mytile = 2 * it + pairI;
        const bool active = mytile < 21;
        if (active) {
            const int tg = kv0 + mytile;
#pragma unroll
            for (int i = 0; i < 8; ++i) {
                const u16* src = Kh + (size_t)(tg * 64 + i * 8 + rh) * HD + 8 * (ck ^ ((i & 1) * 8 + rh));
                __builtin_amdgcn_global_load_lds(
                    (const __attribute__((address_space(1))) u32*)src,
                    (__attribute__((address_space(3))) u32*)(slot + i * 2048 + pt * 16), 16, 0, 0);
            }
#pragma unroll
            for (int i = 0; i < 8; ++i) {
                const u16* src = Vh + (size_t)(i * 16 + rv) * L_SEQ + tg * 64 + 8 * (cvv ^ (rv & 7));
                __builtin_amdgcn_global_load_lds(
                    (const __attribute__((address_space(1))) u32*)src,
                    (__attribute__((address_space(3))) u32*)(slot + 16384 + i * 2048 + pt * 16), 16, 0, 0);
            }
        }
        __syncthreads();                 // drains all staging (vmcnt0 + barrier)
        if (active) {
            // ---- S^T = K Q^T : lane owns row q31 (32 j-values across regs)
            f32x16 sv[2] = {};
            __builtin_amdgcn_s_setprio(1);
#pragma unroll
            for (int js = 0; js < 2; ++js)
#pragma unroll
                for (int kk = 0; kk < 8; ++kk) {
                    int off = (js * 32 + q31) * 256 + ((kk * 32 + hi * 16) ^ ((q31 & 15) << 4));
                    s16x8 kf = *(const s16x8*)(slot + off);
                    sv[js] = __builtin_amdgcn_mfma_f32_32x32x16_bf16(kf, aq[kk], sv[js], 0, 0, 0);
                }
            __builtin_amdgcn_s_setprio(0);

            // ---- softmax: row is lane-local; halves share via one xor-32
            float mx = fmaxf(sv[0][0], sv[1][0]);
#pragma unroll
            for (int e = 1; e < 16; ++e) mx = fmaxf(mx, fmaxf(sv[0][e], sv[1][e]));
            mx = fmaxf(mx, __shfl_xor(mx, 32, 64));
            mx *= sc2;
            const int resc = (mx - mrun) > 11.5f;
            const float mm = resc ? mx : mrun;
            const float fac = resc ? __builtin_amdgcn_exp2f(mrun - mm) : 1.0f;
            mrun = mm;
            float sum = 0.f;
#pragma unroll
            for (int js = 0; js < 2; ++js)
#pragma unroll
                for (int e = 0; e < 16; ++e) {
                    float pv = __builtin_amdgcn_exp2f(sv[js][e] * sc2 - mm);
                    sv[js][e] = pv;
                    sum += pv;
                }
            sum += __shfl_xor(sum, 32, 64);
            lrun = lrun * fac + sum;
            if (__any(resc)) {
#pragma unroll
                for (int ds = 0; ds < 4; ++ds)
#pragma unroll
                    for (int e = 0; e < 16; ++e) acc[ds][e] *= fac;
            }

            // ---- pack P -> B-fragments in-register (cvt_pk + permlane32_swap)
            s16x8 pa[4];
#pragma unroll
            for (int js = 0; js < 2; ++js)
#pragma unroll
                for (int hf = 0; hf < 2; ++hf) {
                    u32 a0 = cvt_pk_bf16(sv[js][hf * 8 + 0], sv[js][hf * 8 + 1]);
                    u32 a1 = cvt_pk_bf16(sv[js][hf * 8 + 2], sv[js][hf * 8 + 3]);
                    u32 b0 = cvt_pk_bf16(sv[js][hf * 8 + 4], sv[js][hf * 8 + 5]);
                    u32 b1 = cvt_pk_bf16(sv[js][hf * 8 + 6], sv[js][hf * 8 + 7]);
                    i32x2 r0 = __builtin_amdgcn_permlane32_swap((int)a0, (int)b0, false, false);
                    i32x2 r1 = __builtin_amdgcn_permlane32_swap((int)a1, (int)b1, false, false);
                    u32x4 fw;
                    fw.x = (u32)r0.x; fw.y = (u32)r1.x; fw.z = (u32)r0.y; fw.w = (u32)r1.y;
                    pa[js * 2 + hf] = __builtin_bit_cast(s16x8, fw);
                }

            // ---- O^T += V^T P^T
            __builtin_amdgcn_s_setprio(1);
#pragma unroll
            for (int jstep = 0; jstep < 4; ++jstep)
#pragma unroll
                for (int ds = 0; ds < 4; ++ds) {
                    int off = 16384 + (ds * 32 + q31) * 128 + ((jstep * 32 + hi * 16) ^ ((q31 & 7) << 4));
                    s16x8 vf = *(const s16x8*)(slot + off);
                    acc[ds] = __builtin_amdgcn_mfma_f32_32x32x16_bf16(vf, pa[jstep], acc[ds], 0, 0, 0);
                }
            __builtin_amdgcn_s_setprio(0);
        }
        __syncthreads();                 // readers done before next overwrite
    }

    // ---- pair merge in LDS: waves 2,3 publish; waves 0,1 combine + output
    float2* mlb = (float2*)(lsm[1]);
    char* accb = lsm[0];
    if (w >= 2) {
        char* base = accb + qhalf * 16384 + lane * 256;
#pragma unroll
        for (int ds = 0; ds < 4; ++ds)
#pragma unroll
            for (int g = 0; g < 4; ++g) {
                f32x4 v4;
#pragma unroll
                for (int e = 0; e < 4; ++e) v4[e] = acc[ds][g * 4 + e];
                *(f32x4*)(base + (((ds * 4 + g) * 16) ^ ((lane & 15) << 4))) = v4;
            }
        if (hi == 0) {
            float2 t2; t2.x = mrun; t2.y = lrun;
            mlb[qhalf * 32 + q31] = t2;
        }
    }
    __syncthreads();
    if (w < 2) {
        float2 ml2 = mlb[qhalf * 32 + q31];
        float M = fmaxf(mrun, ml2.x);
        float wa = exp2f(mrun - M), wb = exp2f(ml2.x - M);
        lrun = lrun * wa + ml2.y * wb;
        mrun = M;
        const char* base = accb + qhalf * 16384 + lane * 256;
#pragma unroll
        for (int ds = 0; ds < 4; ++ds)
#pragma unroll
            for (int g = 0; g < 4; ++g) {
                f32x4 v4 = *(const f32x4*)(base + (((ds * 4 + g) * 16) ^ ((lane & 15) << 4)));
#pragma unroll
                for (int e = 0; e < 4; ++e) acc[ds][g * 4 + e] = acc[ds][g * 4 + e] * wa + v4[e] * wb;
            }
        // d = (e) + 8g + 4hi + 32ds ; q = qrow0 + q31 (lane-local)
        if (mode == 0) {
            const float inv = 1.0f / lrun;
            u16* orow = ob + (size_t)(qrow0 + q31) * DIM + head * HD;
#pragma unroll
            for (int ds = 0; ds < 4; ++ds)
#pragma unroll
                for (int g = 0; g < 4; ++g) {
                    uint2 pk2;
                    pk2.x = cvt_pk_bf16(acc[ds][g * 4 + 0] * inv, acc[ds][g * 4 + 1] * inv);
                    pk2.y = cvt_pk_bf16(acc[ds][g * 4 + 2] * inv, acc[ds][g * 4 + 3] * inv);
                    *(uint2*)(orow + ds * 32 + g * 8 + hi * 4) = pk2;
                }
        } else {
            const int pairo = (head * 21 + (qt - 21)) * 2 + (mode - 1);
            float* Op = Opart + (size_t)pairo * (64 * 128);
            const int rowl = qhalf * 32 + q31;
#pragma unroll
            for (int ds = 0; ds < 4; ++ds)
#pragma unroll
                for (int g = 0; g < 4; ++g) {
                    float4 v4;
                    v4.x = acc[ds][g * 4 + 0]; v4.y = acc[ds][g * 4 + 1];
                    v4.z = acc[ds][g * 4 + 2]; v4.w = acc[ds][g * 4 + 3];
                    *(float4*)(&Op[rowl * 128 + ds * 32 + g * 8 + hi * 4]) = v4;
                }
            if (hi == 0) {
                float2 t2; t2.x = mrun; t2.y = lrun;
                ((float2*)mlp)[(size_t)pairo * 64 + rowl] = t2;
            }
        }
    }
}

// ------------------------------------------------- LSE merge of 2 partials
__global__ __launch_bounds__(256) void k_merge(const float* __restrict__ Opart,
                                               const float* __restrict__ mlp,
                                               u16* __restrict__ ob) {
    const int b = blockIdx.x;
    const int qt2 = b % 21, head = b / 21;
    const int pair = head * 21 + qt2;
    const float* O0 = Opart + (size_t)pair * 2 * 8192;
    const float* O1 = O0 + 8192;
    const int tid = threadIdx.x;
    const int row = tid >> 2, cs = (tid & 3) * 32;
    float2 a = ((const float2*)mlp)[(size_t)pair * 2 * 64 + row];
    float2 c = ((const float2*)mlp)[(size_t)(pair * 2 + 1) * 64 + row];
    float M = fmaxf(a.x, c.x);
    float w0 = exp2f(a.x - M), w1 = exp2f(c.x - M);
    float inv = 1.0f / (w0 * a.y + w1 * c.y);
    w0 *= inv; w1 *= inv;
    const int rowg = BLK_TOK + qt2 * 64 + row;
    u32* orow = (u32*)(ob + (size_t)rowg * DIM + head * HD + cs);
    const float4* p0 = (const float4*)(O0 + row * 128 + cs);
    const float4* p1 = (const float4*)(O1 + row * 128 + cs);
#pragma unroll
    for (int u = 0; u < 8; ++u) {
        float4 x0 = p0[u], x1 = p1[u];
        float o0 = x0.x * w0 + x1.x * w1;
        float o1 = x0.y * w0 + x1.y * w1;
        float o2 = x0.z * w0 + x1.z * w1;
        float o3 = x0.w * w0 + x1.w * w1;
        orow[u * 2]     = (u32)f2b(o0) | ((u32)f2b(o1) << 16);
        orow[u * 2 + 1] = (u32)f2b(o2) | ((u32)f2b(o3) << 16);
    }
}

// ---------------------------------------------------------------- launcher
extern "C" void kernel_launch(void* const* d_in, const int* in_sizes, int n_in,
                              void* d_out, int out_size, void* d_ws, size_t ws_size,
                              hipStream_t stream) {
    const float* x     = (const float*)d_in[0];
    const float* freqs = (const float*)d_in[3];
    const float* Wq    = (const float*)d_in[4];
    const float* bq    = (const float*)d_in[5];
    const float* Wk    = (const float*)d_in[6];
    const float* bk    = (const float*)d_in[7];
    const float* Wv    = (const float*)d_in[8];
    const float* bv    = (const float*)d_in[9];
    const float* Wo    = (const float*)d_in[10];
    const float* bo    = (const float*)d_in[11];
    const float* gq    = (const float*)d_in[12];
    const float* gk    = (const float*)d_in[13];

    const size_t LD = (size_t)L_SEQ * DIM;   // elements
    u16* wt_all  = (u16*)d_ws;                         // 4 * DIM*DIM bf16
    u16* xb      = wt_all + (size_t)4 * DIM * DIM;     // L*DIM
    u16* pre_all = xb + LD;                            // 3 * L*DIM (q,k,v pre)
    u16* qh      = pre_all + 3 * LD;                   // [h][i][d]
    u16* kh2     = qh + LD;
    u16* vt      = kh2 + LD;
    u16* ob      = vt + LD;                            // attn out bf16 [i][c]
    // partials alias pre_all (dead once attention starts): 16.8 MB < 24.8 MB
    float* Opart = (float*)pre_all;                    // 12*21*2*64*128 f32
    float* mlp   = Opart + (size_t)12 * 21 * 2 * 64 * 128;

    k_cvt_x<<<2016, 256, 0, stream>>>(x, xb, (int)(LD / 4));
    k_trans_w<<<dim3(24, 24, 4), 256, 0, stream>>>(Wq, Wk, Wv, Wo, wt_all);
    k_gemm<0><<<dim3(12, 21, 3), 256, 0, stream>>>(xb, wt_all, bq, bk, bv, pre_all);
    k_norm_rope<<<dim3(L_SEQ, 2), 256, 0, stream>>>(pre_all, gq, gk, freqs, qh, kh2);
    k_vtrans<<<dim3(42, 2, NH), 256, 0, stream>>>(pre_all + 2 * LD, vt);
    k_attn<<<dim3(756), 256, 0, stream>>>(qh, kh2, vt, ob, Opart, mlp);
    k_merge<<<dim3(252), 256, 0, stream>>>(Opart, mlp, ob);
    k_gemm<1><<<dim3(12, 21, 1), 256, 0, stream>>>(ob, wt_all + (size_t)3 * DIM * DIM, bo, bo, bo, d_out);
}